// Round 12
// baseline (290.126 us; speedup 1.0000x reference)
//
#include <hip/hip_runtime.h>

namespace {

constexpr int kN = 50000, kE = 200000, kG = 500;
constexpr float kEps = 1e-5f;
constexpr int kNB = (kN + 255) / 256;   // 196 node chunks
constexpr int kEB = (kE + 255) / 256;   // 782 edge chunks

typedef short v8s __attribute__((ext_vector_type(8)));
typedef float v4f __attribute__((ext_vector_type(4)));

__device__ __forceinline__ unsigned short bf16rn(float x) {
    unsigned u = __float_as_uint(x);
    return (unsigned short)((u + 0x7FFFu + ((u >> 16) & 1u)) >> 16);
}
__device__ __forceinline__ float bf16lo(unsigned p) { return __uint_as_float(p << 16); }
__device__ __forceinline__ float bf16hi(unsigned p) { return __uint_as_float(p & 0xFFFF0000u); }
__device__ __forceinline__ unsigned pk2(float a, float b) {
    return (unsigned)bf16rn(a) | ((unsigned)bf16rn(b) << 16);
}

// ---- zero deg + stats. ----
__global__ __launch_bounds__(256) void zero_init(int* __restrict__ deg,
                                                 float* __restrict__ stats) {
    int i = blockIdx.x * 256 + threadIdx.x;
    if (i < kN) deg[i] = 0;
    if (i < 1536) stats[i] = 0.f;   // 3 layers x 8 replicas x 64
}

// ---- degree histogram by dst. ----
__global__ __launch_bounds__(256) void deg_hist(
    const int* __restrict__ ei, int* __restrict__ deg)
{
    int e = blockIdx.x * 256 + threadIdx.x;
    if (e < kE) atomicAdd(&deg[ei[kE + e]], 1);
}

// ---- h = leaky(x @ lin_W + lin_b), fp32 [n][c], MFMA (A=nodes). ----
__global__ __launch_bounds__(1024) void init_h(
    const float* __restrict__ x, const float* __restrict__ W,
    const float* __restrict__ b, float* __restrict__ hbuf)
{
    __shared__ unsigned short sx[256 * 96];
    __shared__ unsigned short sW[32 * 96];
    int t = threadIdx.x;
    for (int i = t; i < 256 * 96; i += 1024) sx[i] = 0;
    for (int i = t; i < 32 * 96; i += 1024) sW[i] = 0;
    __syncthreads();
    int tb = blockIdx.x * 256;
    int cnt = min(256, kN - tb);
    for (int i = t; i < cnt * 75; i += 1024) {
        int n = i / 75, f = i - n * 75;
        sx[n * 96 + f] = bf16rn(x[(size_t)tb * 75 + i]);
    }
    for (int i = t; i < 75 * 32; i += 1024) {
        int f = i >> 5, c = i & 31;
        sW[c * 96 + f] = bf16rn(W[i]);
    }
    __syncthreads();
    int l15 = t & 15, quad = (t >> 4) & 3, w = t >> 6;
    #pragma unroll
    for (int tile = 0; tile < 2; ++tile) {
        v4f acc = {0.f, 0.f, 0.f, 0.f};
        #pragma unroll
        for (int kc = 0; kc < 3; ++kc) {
            v8s a  = *(const v8s*)&sx[(w * 16 + l15) * 96 + kc * 32 + quad * 8];
            v8s bb = *(const v8s*)&sW[(tile * 16 + l15) * 96 + kc * 32 + quad * 8];
            acc = __builtin_amdgcn_mfma_f32_16x16x32_bf16(a, bb, acc, 0, 0, 0);
        }
        int c = tile * 16 + l15;
        float bc = b[c];
        #pragma unroll
        for (int r = 0; r < 4; ++r) {
            int n = tb + w * 16 + quad * 4 + r;
            if (n < kN) {
                float v = acc[r] + bc;
                hbuf[(size_t)n * 32 + c] = v > 0.f ? v : 0.01f * v;
            }
        }
    }
}

// ---- scan phase 1. ----
__global__ __launch_bounds__(256) void scan_part(
    const int* __restrict__ deg, int* __restrict__ blkSum)
{
    __shared__ int sc[256];
    int t = threadIdx.x;
    int idx = blockIdx.x * 256 + t;
    sc[t] = (idx < kN) ? deg[idx] : 0;
    __syncthreads();
    #pragma unroll
    for (int off = 128; off > 0; off >>= 1) {
        if (t < off) sc[t] += sc[t + off];
        __syncthreads();
    }
    if (t == 0) blkSum[blockIdx.x] = sc[0];
}

// ---- scan phase 2. ----
__global__ __launch_bounds__(256) void scan_top(
    const int* __restrict__ blkSum, int* __restrict__ blkOff)
{
    __shared__ int sc[256];
    int t = threadIdx.x;
    int v = (t < kNB) ? blkSum[t] : 0;
    sc[t] = v;
    __syncthreads();
    #pragma unroll
    for (int off = 1; off < 256; off <<= 1) {
        int u = (t >= off) ? sc[t - off] : 0;
        __syncthreads();
        sc[t] += u;
        __syncthreads();
    }
    if (t < kNB) blkOff[t] = sc[t] - v;
}

// ---- scan phase 3 -> cursor. ----
__global__ __launch_bounds__(256) void scan_add(
    const int* __restrict__ deg, const int* __restrict__ blkOff,
    int* __restrict__ cursor)
{
    __shared__ int sc[256];
    int t = threadIdx.x;
    int idx = blockIdx.x * 256 + t;
    int v = (idx < kN) ? deg[idx] : 0;
    sc[t] = v;
    __syncthreads();
    #pragma unroll
    for (int off = 1; off < 256; off <<= 1) {
        int u = (t >= off) ? sc[t - off] : 0;
        __syncthreads();
        sc[t] += u;
        __syncthreads();
    }
    if (idx < kN) cursor[idx] = blkOff[blockIdx.x] + sc[t] - v;
}

// ---- hid = relu(ea@W1+b1), 3 layers, into dst-sorted CSR slots:
// hq[l][pos] = {h01, h23, h4 | src<<16, dst}. ----
__global__ __launch_bounds__(256) void hid_pre(
    const float* __restrict__ ea, const float* __restrict__ W1,
    const float* __restrict__ b1, const int* __restrict__ ei,
    int* __restrict__ cursor, uint4* __restrict__ hq)
{
    __shared__ float sE[256 * 13];
    __shared__ float sW[195];
    int t = threadIdx.x;
    for (int i = t; i < 195; i += 256) sW[i] = (i < 180) ? W1[i] : b1[i - 180];
    int base = blockIdx.x * 256;
    int cnt = min(256, kE - base);
    for (int i = t; i < cnt * 12; i += 256) {
        int el = i / 12, f = i - el * 12;
        sE[el * 13 + f] = ea[(size_t)base * 12 + i];
    }
    __syncthreads();
    if (t >= cnt) return;
    int e = base + t;
    unsigned src = (unsigned)ei[e];
    unsigned dst = (unsigned)ei[kE + e];
    int pos = atomicAdd(&cursor[dst], 1);
    float ef[12];
    #pragma unroll
    for (int j = 0; j < 12; ++j) ef[j] = sE[t * 13 + j];
    #pragma unroll
    for (int l = 0; l < 3; ++l) {
        float h[5];
        #pragma unroll
        for (int k = 0; k < 5; ++k) h[k] = sW[180 + l * 5 + k];
        #pragma unroll
        for (int f = 0; f < 12; ++f)
            #pragma unroll
            for (int k = 0; k < 5; ++k)
                h[k] = fmaf(ef[f], sW[l * 60 + f * 5 + k], h[k]);
        #pragma unroll
        for (int k = 0; k < 5; ++k) h[k] = h[k] > 0.f ? h[k] : 0.f;
        hq[(size_t)l * kE + pos] = make_uint4(
            pk2(h[0], h[1]), pk2(h[2], h[3]),
            (unsigned)bf16rn(h[4]) | (src << 16), dst);
    }
}

// ---- y_root MFMA (A=weights co=d*8+k, B=nodes): packed bf16 dword stores
// into dense Y [n][d][k0..5]us (12 B/lane, 384 B/row = 3 cachelines);
// k==6 -> obuf = root + conv_b. BN prev fused. ----
__global__ __launch_bounds__(1024) void y_root(
    const float* __restrict__ hbuf, float* __restrict__ obuf,
    const float* __restrict__ W2, const float* __restrict__ b2,
    const float* __restrict__ rW, const float* __restrict__ convb,
    const float* __restrict__ statsR,
    const float* __restrict__ gPrev, const float* __restrict__ bPrev,
    int first, unsigned* __restrict__ Ydw)
{
    __shared__ unsigned short sh[256 * 32];
    __shared__ unsigned short sB[256 * 32];
    int t = threadIdx.x;
    int tb = blockIdx.x * 256;
    int cnt = min(256, kN - tb);
    for (int i = t; i < 8192; i += 1024) {
        int co = i >> 5, c = i & 31, d = co >> 3, k = co & 7;
        float v = (k < 5) ? W2[k * 1024 + c * 32 + d]
                : (k == 5) ? b2[c * 32 + d]
                : (k == 6) ? rW[c * 32 + d] : 0.f;
        sB[co * 32 + c] = bf16rn(v);
    }
    if (first) {
        #pragma unroll
        for (int j = 0; j < 8; ++j) {
            int idx = t + j * 1024;
            int nl = idx >> 5, c = idx & 31;
            float v = (nl < cnt) ? hbuf[(size_t)(tb + nl) * 32 + c] : 0.f;
            sh[idx] = bf16rn(v);
        }
    } else {
        int c = t & 31;
        float sum = 0.f, sq = 0.f;
        #pragma unroll
        for (int r = 0; r < 8; ++r) {
            sum += statsR[r * 64 + c];
            sq  += statsR[r * 64 + 32 + c];
        }
        float mu = sum * (1.f / kN);
        float var = sq * (1.f / kN) - mu * mu;
        float ivg = rsqrtf(var + kEps) * gPrev[c];
        float bb = bPrev[c];
        #pragma unroll
        for (int j = 0; j < 8; ++j) {
            int idx = t + j * 1024;
            int nl = idx >> 5;
            float v = 0.f;
            if (nl < cnt) {
                float o = obuf[(size_t)(tb + nl) * 32 + c];
                v = (o - mu) * ivg + bb;
                v = v > 0.f ? v : 0.01f * v;
            }
            sh[idx] = bf16rn(v);
        }
    }
    __syncthreads();
    int l15 = t & 15, quad = (t >> 4) & 3, w = t >> 6;
    int n = tb + w * 16 + l15;
    v8s bn_ = *(const v8s*)&sh[(w * 16 + l15) * 32 + quad * 8];
    #pragma unroll
    for (int i = 0; i < 16; ++i) {
        v8s a = *(const v8s*)&sB[(i * 16 + l15) * 32 + quad * 8];
        v4f acc = {0.f, 0.f, 0.f, 0.f};
        acc = __builtin_amdgcn_mfma_f32_16x16x32_bf16(a, bn_, acc, 0, 0, 0);
        if (n < kN) {
            int cb = i * 16 + quad * 4;
            int d = cb >> 3, koff = cb & 7;
            if (koff == 0) {
                Ydw[(size_t)n * 96 + d * 3]     = pk2(acc[0], acc[1]); // k0,k1
                Ydw[(size_t)n * 96 + d * 3 + 1] = pk2(acc[2], acc[3]); // k2,k3
            } else {
                Ydw[(size_t)n * 96 + d * 3 + 2] = pk2(acc[0], acc[1]); // k4,k5
                obuf[(size_t)n * 32 + d] = acc[2] + convb[d];          // k6
            }
        }
    }
}

// ---- edge_scat: edge-parallel over dst-sorted hq. 32 lanes = channels,
// each group walks 16 consecutive edges: 1 broadcast hq uint4 + 1 dense
// 12 B Y gather (3 cachelines/edge) + 5 FMA; register run-accumulation ->
// lane-coalesced atomic per dst-run. No LDS, no barriers. ----
__global__ __launch_bounds__(256) void edge_scat(
    const uint4* __restrict__ hq, const unsigned* __restrict__ Ydw,
    float* __restrict__ obuf)
{
    int gid = blockIdx.x * 256 + threadIdx.x;
    int grp = gid >> 5;
    if (grp >= kE / 16) return;
    int d = gid & 31;
    int e0 = grp * 16;
    float acc = 0.f;
    unsigned cur = 0xFFFFFFFFu;
    #pragma unroll 4
    for (int i = 0; i < 16; ++i) {
        uint4 q = hq[e0 + i];
        unsigned src = q.z >> 16;
        const unsigned* yr = Ydw + (size_t)src * 96 + d * 3;
        unsigned p0 = yr[0], p1 = yr[1], p2 = yr[2];
        float m = bf16hi(p2);                       // k5 bias-matrix term
        m = fmaf(bf16lo(q.x), bf16lo(p0), m);
        m = fmaf(bf16hi(q.x), bf16hi(p0), m);
        m = fmaf(bf16lo(q.y), bf16lo(p1), m);
        m = fmaf(bf16hi(q.y), bf16hi(p1), m);
        m = fmaf(bf16lo(q.z), bf16lo(p2), m);
        if (q.w != cur) {
            if (cur != 0xFFFFFFFFu) atomicAdd(&obuf[(size_t)cur * 32 + d], acc);
            cur = q.w; acc = m;
        } else acc += m;
    }
    if (cur != 0xFFFFFFFFu) atomicAdd(&obuf[(size_t)cur * 32 + d], acc);
}

// ---- BN stats into 8 replica buffers. ----
__global__ __launch_bounds__(256) void bn_reduce(
    const float* __restrict__ obuf, float* __restrict__ statsR)
{
    __shared__ float ls[256];
    __shared__ float lq[256];
    int t = threadIdx.x;
    int c = t & 31, row = t >> 5;
    float s = 0.f, q = 0.f;
    for (int n = blockIdx.x * 8 + row; n < kN; n += gridDim.x * 8) {
        float v = obuf[(size_t)n * 32 + c];
        s += v; q += v * v;
    }
    ls[t] = s; lq[t] = q;
    __syncthreads();
    if (t < 128) { ls[t] += ls[t + 128]; lq[t] += lq[t + 128]; }
    __syncthreads();
    if (t < 64) { ls[t] += ls[t + 64]; lq[t] += lq[t + 64]; }
    __syncthreads();
    if (t < 32) {
        float* rep = statsR + (blockIdx.x & 7) * 64;
        atomicAdd(&rep[t], ls[t] + ls[t + 32]);
        atomicAdd(&rep[32 + t], lq[t] + lq[t + 32]);
    }
}

// ---- final BN + prediction dot -> vbuf; init out with pred_b. ----
__global__ __launch_bounds__(256) void bn_norm_final(
    const float* __restrict__ obuf, const float* __restrict__ statsR,
    const float* __restrict__ g, const float* __restrict__ b,
    float* __restrict__ vbuf, const float* __restrict__ predW,
    float* __restrict__ out, const float* __restrict__ pred_b)
{
    int idx = blockIdx.x * 256 + threadIdx.x;
    if (idx < kG) out[idx] = pred_b[0];
    if (idx >= kN * 32) return;
    int c = idx & 31;
    float sum = 0.f, sq = 0.f;
    #pragma unroll
    for (int r = 0; r < 8; ++r) {
        sum += statsR[r * 64 + c];
        sq  += statsR[r * 64 + 32 + c];
    }
    float mu = sum * (1.f / kN);
    float var = sq * (1.f / kN) - mu * mu;
    float inv = rsqrtf(var + kEps);
    float v = (obuf[idx] - mu) * inv * g[c] + b[c];
    float pv = v * predW[c];
    #pragma unroll
    for (int off = 16; off > 0; off >>= 1) pv += __shfl_down(pv, off, 32);
    if (c == 0) vbuf[idx >> 5] = pv;
}

// ---- segment readout over sorted batch ids. ----
__global__ __launch_bounds__(256) void seg_readout(
    const float* __restrict__ vbuf, const int* __restrict__ batch,
    float* __restrict__ out)
{
    __shared__ float ls[kG];
    int t = threadIdx.x;
    for (int i = t; i < kG; i += 256) ls[i] = 0.f;
    __syncthreads();
    int base = blockIdx.x * 2048 + t * 8;
    int cur = -1; float acc = 0.f;
    #pragma unroll
    for (int i = 0; i < 8; ++i) {
        int n = base + i;
        if (n >= kN) break;
        int gi = batch[n];
        float val = vbuf[n];
        if (gi != cur) {
            if (cur >= 0) atomicAdd(&ls[cur], acc);
            cur = gi; acc = val;
        } else acc += val;
    }
    if (cur >= 0) atomicAdd(&ls[cur], acc);
    __syncthreads();
    for (int i = t; i < kG; i += 256) {
        float s = ls[i];
        if (s != 0.f) atomicAdd(&out[i], s);
    }
}

} // namespace

extern "C" void kernel_launch(void* const* d_in, const int* in_sizes, int n_in,
                              void* d_out, int out_size, void* d_ws, size_t ws_size,
                              hipStream_t stream)
{
    const float* x      = (const float*)d_in[0];
    const int*   ei     = (const int*)d_in[1];
    const float* ea     = (const float*)d_in[2];
    const int*   batch  = (const int*)d_in[3];
    const float* lin_W  = (const float*)d_in[4];
    const float* lin_b  = (const float*)d_in[5];
    const float* mes_W1 = (const float*)d_in[6];
    const float* mes_b1 = (const float*)d_in[7];
    const float* mes_W2 = (const float*)d_in[8];
    const float* mes_b2 = (const float*)d_in[9];
    const float* root_W = (const float*)d_in[10];
    const float* conv_b = (const float*)d_in[11];
    const float* bn_g   = (const float*)d_in[12];
    const float* bn_b   = (const float*)d_in[13];
    const float* pred_W = (const float*)d_in[14];
    const float* pred_b = (const float*)d_in[15];
    float* out = (float*)d_out;

    // ws: stats[1536 f, 8KB pad] | deg[N] cursor[N] blkSum[256] blkOff[256]
    //     | hbuf[N*32 f] | obuf[N*32 f] | Y[N*192 us dense] | hq[3*E uint4]
    // vbuf[N f] overlays Y (dead after last edge_scat).
    char* wsb = (char*)d_ws;
    float* stats = (float*)wsb;
    int* deg     = (int*)(wsb + 8192);
    int* cursor  = deg + kN;
    int* blkSum  = cursor + kN;
    int* blkOff  = blkSum + 256;
    float* hbuf  = (float*)(blkOff + 256);
    float* obuf  = hbuf + (size_t)kN * 32;
    unsigned short* Yus = (unsigned short*)(obuf + (size_t)kN * 32);
    unsigned* Ydw = (unsigned*)Yus;
    uint4* hq    = (uint4*)(Yus + (size_t)kN * 192);
    float* vbuf  = (float*)Yus;

    zero_init<<<kNB, 256, 0, stream>>>(deg, stats);
    deg_hist<<<kEB, 256, 0, stream>>>(ei, deg);
    init_h<<<kNB, 1024, 0, stream>>>(x, lin_W, lin_b, hbuf);
    scan_part<<<kNB, 256, 0, stream>>>(deg, blkSum);
    scan_top<<<1, 256, 0, stream>>>(blkSum, blkOff);
    scan_add<<<kNB, 256, 0, stream>>>(deg, blkOff, cursor);
    hid_pre<<<kEB, 256, 0, stream>>>(ea, mes_W1, mes_b1, ei, cursor, hq);

    int scatBlocks = ((kE / 16) * 32 + 255) / 256;   // 12500 groups
    for (int l = 0; l < 3; ++l) {
        y_root<<<kNB, 1024, 0, stream>>>(
            hbuf, obuf, mes_W2 + (size_t)l * 5120, mes_b2 + (size_t)l * 1024,
            root_W + (size_t)l * 1024, conv_b + l * 32,
            stats + (l ? (l - 1) * 512 : 0),
            bn_g + (l ? (l - 1) * 32 : 0), bn_b + (l ? (l - 1) * 32 : 0),
            l == 0 ? 1 : 0, Ydw);
        edge_scat<<<scatBlocks, 256, 0, stream>>>(
            hq + (size_t)l * kE, Ydw, obuf);
        bn_reduce<<<512, 256, 0, stream>>>(obuf, stats + l * 512);
    }

    bn_norm_final<<<(kN * 32 + 255) / 256, 256, 0, stream>>>(
        obuf, stats + 2 * 512, bn_g + 64, bn_b + 64, vbuf, pred_W, out, pred_b);
    seg_readout<<<(kN + 2047) / 2048, 256, 0, stream>>>(vbuf, batch, out);
}

// Round 13
// 282.179 us; speedup vs baseline: 1.0282x; 1.0282x over previous
//
#include <hip/hip_runtime.h>

namespace {

constexpr int kN = 50000, kE = 200000, kG = 500;
constexpr float kEps = 1e-5f;
constexpr int kNB = (kN + 255) / 256;   // 196 node chunks
constexpr int kEB = (kE + 255) / 256;   // 782 edge chunks

typedef short v8s __attribute__((ext_vector_type(8)));
typedef float v4f __attribute__((ext_vector_type(4)));

__device__ __forceinline__ unsigned short bf16rn(float x) {
    unsigned u = __float_as_uint(x);
    return (unsigned short)((u + 0x7FFFu + ((u >> 16) & 1u)) >> 16);
}
__device__ __forceinline__ float bf16lo(unsigned p) { return __uint_as_float(p << 16); }
__device__ __forceinline__ float bf16hi(unsigned p) { return __uint_as_float(p & 0xFFFF0000u); }
__device__ __forceinline__ unsigned pk2(float a, float b) {
    return (unsigned)bf16rn(a) | ((unsigned)bf16rn(b) << 16);
}

// ---- degree histogram by dst. ----
__global__ __launch_bounds__(256) void deg_hist(
    const int* __restrict__ ei, int* __restrict__ deg)
{
    int e = blockIdx.x * 256 + threadIdx.x;
    if (e < kE) atomicAdd(&deg[ei[kE + e]], 1);
}

// ---- h = leaky(x @ lin_W + lin_b), fp32 [n][c], MFMA (A=nodes).
// Fused: zero deg (256/block) + stats (block 0). ----
__global__ __launch_bounds__(1024) void init_h(
    const float* __restrict__ x, const float* __restrict__ W,
    const float* __restrict__ b, float* __restrict__ hbuf,
    int* __restrict__ deg, float* __restrict__ stats)
{
    __shared__ unsigned short sx[256 * 96];
    __shared__ unsigned short sW[32 * 96];
    int t = threadIdx.x;
    {
        int z = blockIdx.x * 256 + t;
        if (t < 256 && z < kN) deg[z] = 0;
        if (blockIdx.x == 0) for (int i = t; i < 1536; i += 1024) stats[i] = 0.f;
    }
    for (int i = t; i < 256 * 96; i += 1024) sx[i] = 0;
    for (int i = t; i < 32 * 96; i += 1024) sW[i] = 0;
    __syncthreads();
    int tb = blockIdx.x * 256;
    int cnt = min(256, kN - tb);
    for (int i = t; i < cnt * 75; i += 1024) {
        int n = i / 75, f = i - n * 75;
        sx[n * 96 + f] = bf16rn(x[(size_t)tb * 75 + i]);
    }
    for (int i = t; i < 75 * 32; i += 1024) {
        int f = i >> 5, c = i & 31;
        sW[c * 96 + f] = bf16rn(W[i]);
    }
    __syncthreads();
    int l15 = t & 15, quad = (t >> 4) & 3, w = t >> 6;
    #pragma unroll
    for (int tile = 0; tile < 2; ++tile) {
        v4f acc = {0.f, 0.f, 0.f, 0.f};
        #pragma unroll
        for (int kc = 0; kc < 3; ++kc) {
            v8s a  = *(const v8s*)&sx[(w * 16 + l15) * 96 + kc * 32 + quad * 8];
            v8s bb = *(const v8s*)&sW[(tile * 16 + l15) * 96 + kc * 32 + quad * 8];
            acc = __builtin_amdgcn_mfma_f32_16x16x32_bf16(a, bb, acc, 0, 0, 0);
        }
        int c = tile * 16 + l15;
        float bc = b[c];
        #pragma unroll
        for (int r = 0; r < 4; ++r) {
            int n = tb + w * 16 + quad * 4 + r;
            if (n < kN) {
                float v = acc[r] + bc;
                hbuf[(size_t)n * 32 + c] = v > 0.f ? v : 0.01f * v;
            }
        }
    }
}

// ---- scan phase 1: per-block sums. ----
__global__ __launch_bounds__(256) void scan_part(
    const int* __restrict__ deg, int* __restrict__ blkSum)
{
    __shared__ int sc[256];
    int t = threadIdx.x;
    int idx = blockIdx.x * 256 + t;
    sc[t] = (idx < kN) ? deg[idx] : 0;
    __syncthreads();
    #pragma unroll
    for (int off = 128; off > 0; off >>= 1) {
        if (t < off) sc[t] += sc[t + off];
        __syncthreads();
    }
    if (t == 0) blkSum[blockIdx.x] = sc[0];
}

// ---- scan phase 2 (fused top-scan): each block sums blkSum[0..bid-1]
// itself, then block-local exclusive scan -> cursor. ----
__global__ __launch_bounds__(256) void scan_add(
    const int* __restrict__ deg, const int* __restrict__ blkSum,
    int* __restrict__ cursor)
{
    __shared__ int sc[256];
    __shared__ int sOff;
    int t = threadIdx.x;
    sc[t] = (t < blockIdx.x) ? blkSum[t] : 0;   // blockIdx.x <= 195 < 256
    __syncthreads();
    #pragma unroll
    for (int off = 128; off > 0; off >>= 1) {
        if (t < off) sc[t] += sc[t + off];
        __syncthreads();
    }
    if (t == 0) sOff = sc[0];
    __syncthreads();
    int idx = blockIdx.x * 256 + t;
    int v = (idx < kN) ? deg[idx] : 0;
    sc[t] = v;
    __syncthreads();
    #pragma unroll
    for (int off = 1; off < 256; off <<= 1) {
        int u = (t >= off) ? sc[t - off] : 0;
        __syncthreads();
        sc[t] += u;
        __syncthreads();
    }
    if (idx < kN) cursor[idx] = sOff + sc[t] - v;
}

// ---- hid = relu(ea@W1+b1), 3 layers, into dst-sorted CSR slots:
// hq[l][pos] = {h01, h23, h4 | src<<16, dst}. ----
__global__ __launch_bounds__(256) void hid_pre(
    const float* __restrict__ ea, const float* __restrict__ W1,
    const float* __restrict__ b1, const int* __restrict__ ei,
    int* __restrict__ cursor, uint4* __restrict__ hq)
{
    __shared__ float sE[256 * 13];
    __shared__ float sW[195];
    int t = threadIdx.x;
    for (int i = t; i < 195; i += 256) sW[i] = (i < 180) ? W1[i] : b1[i - 180];
    int base = blockIdx.x * 256;
    int cnt = min(256, kE - base);
    for (int i = t; i < cnt * 12; i += 256) {
        int el = i / 12, f = i - el * 12;
        sE[el * 13 + f] = ea[(size_t)base * 12 + i];
    }
    __syncthreads();
    if (t >= cnt) return;
    int e = base + t;
    unsigned src = (unsigned)ei[e];
    unsigned dst = (unsigned)ei[kE + e];
    int pos = atomicAdd(&cursor[dst], 1);
    float ef[12];
    #pragma unroll
    for (int j = 0; j < 12; ++j) ef[j] = sE[t * 13 + j];
    #pragma unroll
    for (int l = 0; l < 3; ++l) {
        float h[5];
        #pragma unroll
        for (int k = 0; k < 5; ++k) h[k] = sW[180 + l * 5 + k];
        #pragma unroll
        for (int f = 0; f < 12; ++f)
            #pragma unroll
            for (int k = 0; k < 5; ++k)
                h[k] = fmaf(ef[f], sW[l * 60 + f * 5 + k], h[k]);
        #pragma unroll
        for (int k = 0; k < 5; ++k) h[k] = h[k] > 0.f ? h[k] : 0.f;
        hq[(size_t)l * kE + pos] = make_uint4(
            pk2(h[0], h[1]), pk2(h[2], h[3]),
            (unsigned)bf16rn(h[4]) | (src << 16), dst);
    }
}

// ---- y_root MFMA (A=weights co=d*8+k, B=nodes): packed bf16 dword stores
// into dense Y [n][d][k0..5]us; k==6 -> obuf = root + conv_b. BN fused. ----
__global__ __launch_bounds__(1024) void y_root(
    const float* __restrict__ hbuf, float* __restrict__ obuf,
    const float* __restrict__ W2, const float* __restrict__ b2,
    const float* __restrict__ rW, const float* __restrict__ convb,
    const float* __restrict__ statsR,
    const float* __restrict__ gPrev, const float* __restrict__ bPrev,
    int first, unsigned* __restrict__ Ydw)
{
    __shared__ unsigned short sh[256 * 32];
    __shared__ unsigned short sB[256 * 32];
    int t = threadIdx.x;
    int tb = blockIdx.x * 256;
    int cnt = min(256, kN - tb);
    for (int i = t; i < 8192; i += 1024) {
        int co = i >> 5, c = i & 31, d = co >> 3, k = co & 7;
        float v = (k < 5) ? W2[k * 1024 + c * 32 + d]
                : (k == 5) ? b2[c * 32 + d]
                : (k == 6) ? rW[c * 32 + d] : 0.f;
        sB[co * 32 + c] = bf16rn(v);
    }
    if (first) {
        #pragma unroll
        for (int j = 0; j < 8; ++j) {
            int idx = t + j * 1024;
            int nl = idx >> 5, c = idx & 31;
            float v = (nl < cnt) ? hbuf[(size_t)(tb + nl) * 32 + c] : 0.f;
            sh[idx] = bf16rn(v);
        }
    } else {
        int c = t & 31;
        float sum = 0.f, sq = 0.f;
        #pragma unroll
        for (int r = 0; r < 8; ++r) {
            sum += statsR[r * 64 + c];
            sq  += statsR[r * 64 + 32 + c];
        }
        float mu = sum * (1.f / kN);
        float var = sq * (1.f / kN) - mu * mu;
        float ivg = rsqrtf(var + kEps) * gPrev[c];
        float bb = bPrev[c];
        #pragma unroll
        for (int j = 0; j < 8; ++j) {
            int idx = t + j * 1024;
            int nl = idx >> 5;
            float v = 0.f;
            if (nl < cnt) {
                float o = obuf[(size_t)(tb + nl) * 32 + c];
                v = (o - mu) * ivg + bb;
                v = v > 0.f ? v : 0.01f * v;
            }
            sh[idx] = bf16rn(v);
        }
    }
    __syncthreads();
    int l15 = t & 15, quad = (t >> 4) & 3, w = t >> 6;
    int n = tb + w * 16 + l15;
    v8s bn_ = *(const v8s*)&sh[(w * 16 + l15) * 32 + quad * 8];
    #pragma unroll
    for (int i = 0; i < 16; ++i) {
        v8s a = *(const v8s*)&sB[(i * 16 + l15) * 32 + quad * 8];
        v4f acc = {0.f, 0.f, 0.f, 0.f};
        acc = __builtin_amdgcn_mfma_f32_16x16x32_bf16(a, bn_, acc, 0, 0, 0);
        if (n < kN) {
            int cb = i * 16 + quad * 4;
            int d = cb >> 3, koff = cb & 7;
            if (koff == 0) {
                Ydw[(size_t)n * 96 + d * 3]     = pk2(acc[0], acc[1]); // k0,k1
                Ydw[(size_t)n * 96 + d * 3 + 1] = pk2(acc[2], acc[3]); // k2,k3
            } else {
                Ydw[(size_t)n * 96 + d * 3 + 2] = pk2(acc[0], acc[1]); // k4,k5
                obuf[(size_t)n * 32 + d] = acc[2] + convb[d];          // k6
            }
        }
    }
}

// ---- edge_scat: 4 edges/group, fully unrolled, ALL loads issued upfront
// (max outstanding-load concurrency); run-merged lane-coalesced atomics.
// 50000 groups -> 25000 waves. ----
__global__ __launch_bounds__(256) void edge_scat(
    const uint4* __restrict__ hq, const unsigned* __restrict__ Ydw,
    float* __restrict__ obuf)
{
    int gid = blockIdx.x * 256 + threadIdx.x;
    int grp = gid >> 5;                 // exactly kE/4 = 50000 groups
    int d = gid & 31;
    int e0 = grp * 4;
    uint4 q0 = hq[e0], q1 = hq[e0 + 1], q2 = hq[e0 + 2], q3 = hq[e0 + 3];
    const unsigned* y0 = Ydw + (size_t)(q0.z >> 16) * 96 + d * 3;
    const unsigned* y1 = Ydw + (size_t)(q1.z >> 16) * 96 + d * 3;
    const unsigned* y2 = Ydw + (size_t)(q2.z >> 16) * 96 + d * 3;
    const unsigned* y3 = Ydw + (size_t)(q3.z >> 16) * 96 + d * 3;
    unsigned p00 = y0[0], p01 = y0[1], p02 = y0[2];
    unsigned p10 = y1[0], p11 = y1[1], p12 = y1[2];
    unsigned p20 = y2[0], p21 = y2[1], p22 = y2[2];
    unsigned p30 = y3[0], p31 = y3[1], p32 = y3[2];
    float m0 = bf16hi(p02);
    m0 = fmaf(bf16lo(q0.x), bf16lo(p00), m0);
    m0 = fmaf(bf16hi(q0.x), bf16hi(p00), m0);
    m0 = fmaf(bf16lo(q0.y), bf16lo(p01), m0);
    m0 = fmaf(bf16hi(q0.y), bf16hi(p01), m0);
    m0 = fmaf(bf16lo(q0.z), bf16lo(p02), m0);
    float m1 = bf16hi(p12);
    m1 = fmaf(bf16lo(q1.x), bf16lo(p10), m1);
    m1 = fmaf(bf16hi(q1.x), bf16hi(p10), m1);
    m1 = fmaf(bf16lo(q1.y), bf16lo(p11), m1);
    m1 = fmaf(bf16hi(q1.y), bf16hi(p11), m1);
    m1 = fmaf(bf16lo(q1.z), bf16lo(p12), m1);
    float m2 = bf16hi(p22);
    m2 = fmaf(bf16lo(q2.x), bf16lo(p20), m2);
    m2 = fmaf(bf16hi(q2.x), bf16hi(p20), m2);
    m2 = fmaf(bf16lo(q2.y), bf16lo(p21), m2);
    m2 = fmaf(bf16hi(q2.y), bf16hi(p21), m2);
    m2 = fmaf(bf16lo(q2.z), bf16lo(p22), m2);
    float m3 = bf16hi(p32);
    m3 = fmaf(bf16lo(q3.x), bf16lo(p30), m3);
    m3 = fmaf(bf16hi(q3.x), bf16hi(p30), m3);
    m3 = fmaf(bf16lo(q3.y), bf16lo(p31), m3);
    m3 = fmaf(bf16hi(q3.y), bf16hi(p31), m3);
    m3 = fmaf(bf16lo(q3.z), bf16lo(p32), m3);
    // run-merge over dst-sorted 4-edge window
    float acc = m0;
    unsigned cur = q0.w;
    if (q1.w == cur) acc += m1;
    else { atomicAdd(&obuf[(size_t)cur * 32 + d], acc); cur = q1.w; acc = m1; }
    if (q2.w == cur) acc += m2;
    else { atomicAdd(&obuf[(size_t)cur * 32 + d], acc); cur = q2.w; acc = m2; }
    if (q3.w == cur) acc += m3;
    else { atomicAdd(&obuf[(size_t)cur * 32 + d], acc); cur = q3.w; acc = m3; }
    atomicAdd(&obuf[(size_t)cur * 32 + d], acc);
}

// ---- BN stats into 8 replica buffers. ----
__global__ __launch_bounds__(256) void bn_reduce(
    const float* __restrict__ obuf, float* __restrict__ statsR)
{
    __shared__ float ls[256];
    __shared__ float lq[256];
    int t = threadIdx.x;
    int c = t & 31, row = t >> 5;
    float s = 0.f, q = 0.f;
    for (int n = blockIdx.x * 8 + row; n < kN; n += gridDim.x * 8) {
        float v = obuf[(size_t)n * 32 + c];
        s += v; q += v * v;
    }
    ls[t] = s; lq[t] = q;
    __syncthreads();
    if (t < 128) { ls[t] += ls[t + 128]; lq[t] += lq[t + 128]; }
    __syncthreads();
    if (t < 64) { ls[t] += ls[t + 64]; lq[t] += lq[t + 64]; }
    __syncthreads();
    if (t < 32) {
        float* rep = statsR + (blockIdx.x & 7) * 64;
        atomicAdd(&rep[t], ls[t] + ls[t + 32]);
        atomicAdd(&rep[32 + t], lq[t] + lq[t + 32]);
    }
}

// ---- final BN + prediction dot -> vbuf; init out with pred_b. ----
__global__ __launch_bounds__(256) void bn_norm_final(
    const float* __restrict__ obuf, const float* __restrict__ statsR,
    const float* __restrict__ g, const float* __restrict__ b,
    float* __restrict__ vbuf, const float* __restrict__ predW,
    float* __restrict__ out, const float* __restrict__ pred_b)
{
    int idx = blockIdx.x * 256 + threadIdx.x;
    if (idx < kG) out[idx] = pred_b[0];
    if (idx >= kN * 32) return;
    int c = idx & 31;
    float sum = 0.f, sq = 0.f;
    #pragma unroll
    for (int r = 0; r < 8; ++r) {
        sum += statsR[r * 64 + c];
        sq  += statsR[r * 64 + 32 + c];
    }
    float mu = sum * (1.f / kN);
    float var = sq * (1.f / kN) - mu * mu;
    float inv = rsqrtf(var + kEps);
    float v = (obuf[idx] - mu) * inv * g[c] + b[c];
    float pv = v * predW[c];
    #pragma unroll
    for (int off = 16; off > 0; off >>= 1) pv += __shfl_down(pv, off, 32);
    if (c == 0) vbuf[idx >> 5] = pv;
}

// ---- segment readout over sorted batch ids. ----
__global__ __launch_bounds__(256) void seg_readout(
    const float* __restrict__ vbuf, const int* __restrict__ batch,
    float* __restrict__ out)
{
    __shared__ float ls[kG];
    int t = threadIdx.x;
    for (int i = t; i < kG; i += 256) ls[i] = 0.f;
    __syncthreads();
    int base = blockIdx.x * 2048 + t * 8;
    int cur = -1; float acc = 0.f;
    #pragma unroll
    for (int i = 0; i < 8; ++i) {
        int n = base + i;
        if (n >= kN) break;
        int gi = batch[n];
        float val = vbuf[n];
        if (gi != cur) {
            if (cur >= 0) atomicAdd(&ls[cur], acc);
            cur = gi; acc = val;
        } else acc += val;
    }
    if (cur >= 0) atomicAdd(&ls[cur], acc);
    __syncthreads();
    for (int i = t; i < kG; i += 256) {
        float s = ls[i];
        if (s != 0.f) atomicAdd(&out[i], s);
    }
}

} // namespace

extern "C" void kernel_launch(void* const* d_in, const int* in_sizes, int n_in,
                              void* d_out, int out_size, void* d_ws, size_t ws_size,
                              hipStream_t stream)
{
    const float* x      = (const float*)d_in[0];
    const int*   ei     = (const int*)d_in[1];
    const float* ea     = (const float*)d_in[2];
    const int*   batch  = (const int*)d_in[3];
    const float* lin_W  = (const float*)d_in[4];
    const float* lin_b  = (const float*)d_in[5];
    const float* mes_W1 = (const float*)d_in[6];
    const float* mes_b1 = (const float*)d_in[7];
    const float* mes_W2 = (const float*)d_in[8];
    const float* mes_b2 = (const float*)d_in[9];
    const float* root_W = (const float*)d_in[10];
    const float* conv_b = (const float*)d_in[11];
    const float* bn_g   = (const float*)d_in[12];
    const float* bn_b   = (const float*)d_in[13];
    const float* pred_W = (const float*)d_in[14];
    const float* pred_b = (const float*)d_in[15];
    float* out = (float*)d_out;

    // ws: stats[1536 f, 8KB pad] | deg[N] cursor[N] blkSum[256]
    //     | hbuf[N*32 f] | obuf[N*32 f] | Y[N*192 us dense] | hq[3*E uint4]
    // vbuf[N f] overlays Y (dead after last edge_scat).
    char* wsb = (char*)d_ws;
    float* stats = (float*)wsb;
    int* deg     = (int*)(wsb + 8192);
    int* cursor  = deg + kN;
    int* blkSum  = cursor + kN;
    float* hbuf  = (float*)(blkSum + 256);
    float* obuf  = hbuf + (size_t)kN * 32;
    unsigned short* Yus = (unsigned short*)(obuf + (size_t)kN * 32);
    unsigned* Ydw = (unsigned*)Yus;
    uint4* hq    = (uint4*)(Yus + (size_t)kN * 192);
    float* vbuf  = (float*)Yus;

    init_h<<<kNB, 1024, 0, stream>>>(x, lin_W, lin_b, hbuf, deg, stats);
    deg_hist<<<kEB, 256, 0, stream>>>(ei, deg);
    scan_part<<<kNB, 256, 0, stream>>>(deg, blkSum);
    scan_add<<<kNB, 256, 0, stream>>>(deg, blkSum, cursor);
    hid_pre<<<kEB, 256, 0, stream>>>(ea, mes_W1, mes_b1, ei, cursor, hq);

    int scatBlocks = (kE / 4) * 32 / 256;   // 6250
    for (int l = 0; l < 3; ++l) {
        y_root<<<kNB, 1024, 0, stream>>>(
            hbuf, obuf, mes_W2 + (size_t)l * 5120, mes_b2 + (size_t)l * 1024,
            root_W + (size_t)l * 1024, conv_b + l * 32,
            stats + (l ? (l - 1) * 512 : 0),
            bn_g + (l ? (l - 1) * 32 : 0), bn_b + (l ? (l - 1) * 32 : 0),
            l == 0 ? 1 : 0, Ydw);
        edge_scat<<<scatBlocks, 256, 0, stream>>>(
            hq + (size_t)l * kE, Ydw, obuf);
        bn_reduce<<<512, 256, 0, stream>>>(obuf, stats + l * 512);
    }

    bn_norm_final<<<(kN * 32 + 255) / 256, 256, 0, stream>>>(
        obuf, stats + 2 * 512, bn_g + 64, bn_b + 64, vbuf, pred_W, out, pred_b);
    seg_readout<<<(kN + 2047) / 2048, 256, 0, stream>>>(vbuf, batch, out);
}